// Round 4
// baseline (2406.933 us; speedup 1.0000x reference)
//
#include <hip/hip_runtime.h>

#define RCH 64
#define SCH 128
#define NLAYERS 30
#define TLEN 16384
#define NB 4
#define TT 64
#define TW 16
#define LDSPAD 68

// ---------------- weight packing ----------------
// wfg[i][c][o][4] = {Wf[i][o][c][0], Wf[i][o][c][1], Wg[i][o][c][0], Wg[i][o][c][1]}
// wrs[i][c][o][4] = {Wr[i][o][c], Ws[i][o][c], Ws[i][o+64][c], 0}
__global__ __launch_bounds__(256) void pack_weights(
    const float* __restrict__ Wf, const float* __restrict__ Wg,
    const float* __restrict__ Wr, const float* __restrict__ Ws,
    float* __restrict__ wfg, float* __restrict__ wrs)
{
    int t = blockIdx.x * 256 + threadIdx.x;      // < 30*64*64
    int o = t & 63, c = (t >> 6) & 63, i = t >> 12;
    if (i >= NLAYERS) return;
    size_t fidx = (((size_t)i * RCH + o) * RCH + c) * 2;
    float4 wv;
    wv.x = Wf[fidx];     wv.y = Wf[fidx + 1];
    wv.z = Wg[fidx];     wv.w = Wg[fidx + 1];
    *(float4*)&wfg[(((size_t)i * RCH + c) * RCH + o) * 4] = wv;
    float4 rv;
    rv.x = Wr[((size_t)i * RCH + o) * RCH + c];
    rv.y = Ws[((size_t)i * SCH + o) * RCH + c];
    rv.z = Ws[((size_t)i * SCH + o + 64) * RCH + c];
    rv.w = 0.f;
    *(float4*)&wrs[(((size_t)i * RCH + c) * RCH + o) * 4] = rv;
}

// wp2[c][o][2] = {w_post[o][c], w_post[o+64][c]}; same for w_o1
__global__ __launch_bounds__(256) void pack_head(
    const float* __restrict__ w_post, const float* __restrict__ w_o1,
    float* __restrict__ wp2, float* __restrict__ wo1p)
{
    int t = blockIdx.x * 256 + threadIdx.x;      // < 128*64
    int o = t & 63, c = t >> 6;                  // c < 128
    float2 a;
    a.x = w_post[o * SCH + c]; a.y = w_post[(o + 64) * SCH + c];
    *(float2*)&wp2[(c * 64 + o) * 2] = a;
    float2 b1;
    b1.x = w_o1[o * SCH + c];  b1.y = w_o1[(o + 64) * SCH + c];
    *(float2*)&wo1p[(c * 64 + o) * 2] = b1;
}

// ---------------- initial causal conv (k=2, d=1) ----------------
__global__ __launch_bounds__(256) void init_conv(
    const float* __restrict__ x, const float* __restrict__ wc,
    const float* __restrict__ bc, float* __restrict__ h0)
{
    int idx = blockIdx.x * 256 + threadIdx.x;    // b<<20 | c<<14 | t
    int t = idx & (TLEN - 1);
    int c = (idx >> 14) & 63;
    int b = idx >> 20;
    float xc = x[b * TLEN + t];
    float xp = (t > 0) ? x[b * TLEN + t - 1] : 0.f;
    h0[idx] = fmaf(wc[c * 2], xp, fmaf(wc[c * 2 + 1], xc, bc[c]));
}

// ---------------- one WaveNet layer ----------------
__global__ __launch_bounds__(256, 4) void layer_kernel(
    const float* __restrict__ hin, float* __restrict__ hout,
    float* __restrict__ skip,
    const float* __restrict__ wfg, const float* __restrict__ wrs,
    const float* __restrict__ bf, const float* __restrict__ bg,
    const float* __restrict__ br, const float* __restrict__ bs,
    int layer, int dil, int first)
{
    __shared__ float hcur[RCH * LDSPAD];
    __shared__ float hpo[RCH * LDSPAD];   // hprev; later aliased as gated-out tile
    int tid = threadIdx.x;
    int bx = blockIdx.x;
    int b = bx >> 8;
    int t0 = (bx & 255) * TT;
    const float* hb = hin + (size_t)b * RCH * TLEN;

    {   // stage h[t] (vector) and h[t-d] (scalar, zero-padded) tiles
        int c = tid >> 2, q = tid & 3;
        const float* src = hb + (size_t)c * TLEN + t0;
        float* dc = &hcur[c * LDSPAD];
        float* dp = &hpo[c * LDSPAD];
        #pragma unroll
        for (int u = 0; u < 4; ++u) {
            int j = q * 16 + u * 4;
            *(float4*)&dc[j] = *(const float4*)&src[j];
            int base = t0 + j - dil;
            float4 pv;
            pv.x = (base     >= 0) ? src[j     - dil] : 0.f;
            pv.y = (base + 1 >= 0) ? src[j + 1 - dil] : 0.f;
            pv.z = (base + 2 >= 0) ? src[j + 2 - dil] : 0.f;
            pv.w = (base + 3 >= 0) ? src[j + 3 - dil] : 0.f;
            *(float4*)&dp[j] = pv;
        }
    }
    __syncthreads();

    int lane = tid & 63, wv = tid >> 6;
    int tb = wv * TW;
    int o = lane;

    // phase 1: f/g dilated convs
    float f[TW], g[TW];
    float bfv = bf[layer * RCH + o], bgv = bg[layer * RCH + o];
    #pragma unroll
    for (int t = 0; t < TW; ++t) { f[t] = bfv; g[t] = bgv; }
    const float4* wfp = (const float4*)(wfg + (size_t)layer * RCH * RCH * 4);
    #pragma unroll 4
    for (int c = 0; c < RCH; ++c) {
        float4 w = wfp[c * RCH + o];
        const float* hp = &hpo[c * LDSPAD + tb];
        const float* hc = &hcur[c * LDSPAD + tb];
        #pragma unroll
        for (int t = 0; t < TW; ++t) {
            float xp = hp[t], xc = hc[t];
            f[t] = fmaf(w.x, xp, f[t]);
            f[t] = fmaf(w.y, xc, f[t]);
            g[t] = fmaf(w.z, xp, g[t]);
            g[t] = fmaf(w.w, xc, g[t]);
        }
    }
    // gated activation: out = tanh(f) * sigmoid(g)
    #pragma unroll
    for (int t = 0; t < TW; ++t) {
        float e2 = __expf(2.f * f[t]);
        float th = 1.f - 2.f * __builtin_amdgcn_rcpf(e2 + 1.f);
        float sg = __builtin_amdgcn_rcpf(1.f + __expf(-g[t]));
        f[t] = th * sg;
    }
    // write out tile into hpo alias (own columns only -> wave-local, no barrier)
    #pragma unroll
    for (int t = 0; t < TW; ++t) hpo[o * LDSPAD + tb + t] = f[t];

    // phase 2: residual (Wr) + skip (Ws) 1x1 convs
    float rr[TW], s0[TW], s1[TW];
    float brv = br[layer * RCH + o];
    float bs0 = bs[layer * SCH + o], bs1 = bs[layer * SCH + 64 + o];
    #pragma unroll
    for (int t = 0; t < TW; ++t) { rr[t] = brv; s0[t] = bs0; s1[t] = bs1; }
    const float4* wrp = (const float4*)(wrs + (size_t)layer * RCH * RCH * 4);
    #pragma unroll 4
    for (int c = 0; c < RCH; ++c) {
        float4 w = wrp[c * RCH + o];
        const float* ov = &hpo[c * LDSPAD + tb];
        #pragma unroll
        for (int t = 0; t < TW; ++t) {
            float xv = ov[t];
            rr[t] = fmaf(w.x, xv, rr[t]);
            s0[t] = fmaf(w.y, xv, s0[t]);
            s1[t] = fmaf(w.z, xv, s1[t]);
        }
    }
    // residual add + store new h
    #pragma unroll
    for (int t = 0; t < TW; ++t) rr[t] += hcur[o * LDSPAD + tb + t];
    float* hob = hout + ((size_t)b * RCH + o) * TLEN + t0 + tb;
    #pragma unroll
    for (int u = 0; u < 4; ++u)
        *(float4*)&hob[u * 4] = make_float4(rr[u*4], rr[u*4+1], rr[u*4+2], rr[u*4+3]);
    // skip accumulate
    float* sk0 = skip + ((size_t)b * SCH + o) * TLEN + t0 + tb;
    float* sk1 = sk0 + 64 * TLEN;
    if (first) {
        #pragma unroll
        for (int u = 0; u < 4; ++u) {
            *(float4*)&sk0[u*4] = make_float4(s0[u*4], s0[u*4+1], s0[u*4+2], s0[u*4+3]);
            *(float4*)&sk1[u*4] = make_float4(s1[u*4], s1[u*4+1], s1[u*4+2], s1[u*4+3]);
        }
    } else {
        #pragma unroll
        for (int u = 0; u < 4; ++u) {
            float4 p0 = *(const float4*)&sk0[u*4];
            float4 p1 = *(const float4*)&sk1[u*4];
            p0.x += s0[u*4]; p0.y += s0[u*4+1]; p0.z += s0[u*4+2]; p0.w += s0[u*4+3];
            p1.x += s1[u*4]; p1.y += s1[u*4+1]; p1.z += s1[u*4+2]; p1.w += s1[u*4+3];
            *(float4*)&sk0[u*4] = p0;
            *(float4*)&sk1[u*4] = p1;
        }
    }
}

// ---------------- output head: relu(post) -> relu(o1) -> o2 ----------------
__global__ __launch_bounds__(256, 4) void head_kernel(
    const float* __restrict__ skip, const float* __restrict__ wp2,
    const float* __restrict__ wo1p, const float* __restrict__ wo2,
    const float* __restrict__ b_post, const float* __restrict__ b_o1,
    const float* __restrict__ b_o2, float* __restrict__ out)
{
    __shared__ float sk[SCH * LDSPAD];
    int tid = threadIdx.x;
    int bx = blockIdx.x;
    int b = bx >> 8;
    int t0 = (bx & 255) * TT;
    {   // stage skip tile [128][64]
        int c = tid >> 1, half = tid & 1;
        const float* src = skip + ((size_t)b * SCH + c) * TLEN + t0;
        float* dst = &sk[c * LDSPAD];
        #pragma unroll
        for (int u = 0; u < 8; ++u) {
            int j = half * 32 + u * 4;
            *(float4*)&dst[j] = *(const float4*)&src[j];
        }
    }
    __syncthreads();

    int lane = tid & 63, wv = tid >> 6;
    int tb = wv * TW;
    int o = lane;

    // phase A: s1 = relu(w_post @ skip + b_post)
    float a0[TW], a1[TW];
    float bp0 = b_post[o], bp1 = b_post[o + 64];
    #pragma unroll
    for (int t = 0; t < TW; ++t) { a0[t] = bp0; a1[t] = bp1; }
    #pragma unroll 4
    for (int c = 0; c < SCH; ++c) {
        float2 w = *(const float2*)&wp2[(c * 64 + o) * 2];
        const float* sv = &sk[c * LDSPAD + tb];
        #pragma unroll
        for (int t = 0; t < TW; ++t) {
            a0[t] = fmaf(w.x, sv[t], a0[t]);
            a1[t] = fmaf(w.y, sv[t], a1[t]);
        }
    }
    #pragma unroll
    for (int t = 0; t < TW; ++t) {
        a0[t] = fmaxf(a0[t], 0.f);
        a1[t] = fmaxf(a1[t], 0.f);
    }
    #pragma unroll
    for (int t = 0; t < TW; ++t) {
        sk[o * LDSPAD + tb + t] = a0[t];
        sk[(o + 64) * LDSPAD + tb + t] = a1[t];
    }

    // phase B: s2 = relu(w_o1 @ s1 + b_o1)
    float c0[TW], c1[TW];
    float bq0 = b_o1[o], bq1 = b_o1[o + 64];
    #pragma unroll
    for (int t = 0; t < TW; ++t) { c0[t] = bq0; c1[t] = bq1; }
    #pragma unroll 4
    for (int c = 0; c < SCH; ++c) {
        float2 w = *(const float2*)&wo1p[(c * 64 + o) * 2];
        const float* sv = &sk[c * LDSPAD + tb];
        #pragma unroll
        for (int t = 0; t < TW; ++t) {
            c0[t] = fmaf(w.x, sv[t], c0[t]);
            c1[t] = fmaf(w.y, sv[t], c1[t]);
        }
    }
    #pragma unroll
    for (int t = 0; t < TW; ++t) {
        c0[t] = fmaxf(c0[t], 0.f);
        c1[t] = fmaxf(c1[t], 0.f);
    }
    #pragma unroll
    for (int t = 0; t < TW; ++t) {
        sk[o * LDSPAD + tb + t] = c0[t];
        sk[(o + 64) * LDSPAD + tb + t] = c1[t];
    }

    // phase C: out = w_o2 @ s2 + b_o2 (4 lanes per t, 32 c each)
    int tt = lane & 15;
    int cg = lane >> 4;
    float acc = 0.f;
    #pragma unroll
    for (int cc = 0; cc < 32; ++cc) {
        int c = cg * 32 + cc;
        acc = fmaf(wo2[c], sk[c * LDSPAD + tb + tt], acc);
    }
    acc += __shfl_xor(acc, 16);
    acc += __shfl_xor(acc, 32);
    if (lane < 16)
        out[(size_t)b * TLEN + t0 + tb + tt] = acc + b_o2[0];
}

// ---------------- host ----------------
extern "C" void kernel_launch(void* const* d_in, const int* in_sizes, int n_in,
                              void* d_out, int out_size, void* d_ws, size_t ws_size,
                              hipStream_t stream) {
    const float* x        = (const float*)d_in[0];
    const float* w_causal = (const float*)d_in[1];
    const float* b_causal = (const float*)d_in[2];
    const float* Wf       = (const float*)d_in[3];
    const float* bf       = (const float*)d_in[4];
    const float* Wg       = (const float*)d_in[5];
    const float* bg       = (const float*)d_in[6];
    const float* Wr       = (const float*)d_in[7];
    const float* br       = (const float*)d_in[8];
    const float* Ws       = (const float*)d_in[9];
    const float* bs       = (const float*)d_in[10];
    const float* w_post   = (const float*)d_in[11];
    const float* b_post   = (const float*)d_in[12];
    const float* w_o1     = (const float*)d_in[13];
    const float* b_o1     = (const float*)d_in[14];
    const float* w_o2     = (const float*)d_in[15];
    const float* b_o2     = (const float*)d_in[16];

    float* ws   = (float*)d_ws;
    float* h0   = ws;                      // 4*64*16384
    float* h1   = h0 + (size_t)NB * RCH * TLEN;
    float* skip = h1 + (size_t)NB * RCH * TLEN;   // 4*128*16384
    float* wfg  = skip + (size_t)NB * SCH * TLEN; // 30*64*64*4
    float* wrs  = wfg + (size_t)NLAYERS * RCH * RCH * 4;
    float* wp2  = wrs + (size_t)NLAYERS * RCH * RCH * 4;  // 128*64*2
    float* wo1p = wp2 + SCH * 64 * 2;

    pack_weights<<<480, 256, 0, stream>>>(Wf, Wg, Wr, Ws, wfg, wrs);
    pack_head<<<32, 256, 0, stream>>>(w_post, w_o1, wp2, wo1p);
    init_conv<<<16384, 256, 0, stream>>>(x, w_causal, b_causal, h0);

    float* hin = h0;
    float* hout = h1;
    for (int i = 0; i < NLAYERS; ++i) {
        int d = 1 << (i % 10);
        layer_kernel<<<1024, 256, 0, stream>>>(hin, hout, skip, wfg, wrs,
                                               bf, bg, br, bs, i, d, i == 0);
        float* tmp = hin; hin = hout; hout = tmp;
    }
    head_kernel<<<1024, 256, 0, stream>>>(skip, wp2, wo1p, w_o2,
                                          b_post, b_o1, b_o2, (float*)d_out);
}

// Round 6
// 798.024 us; speedup vs baseline: 3.0161x; 3.0161x over previous
//
#include <hip/hip_runtime.h>

#define RCH 64
#define SCH 128
#define NLAYERS 30
#define TLEN 16384
#define NB 4

typedef _Float16 f16;
typedef _Float16 f16x8 __attribute__((ext_vector_type(8)));
typedef float f32x4 __attribute__((ext_vector_type(4)));

// ---------------- pack all weights into per-fragment f16 layout ----------------
// A-frag layout for mfma_f32_16x16x32_f16: lane l carries A[m=(l&15)][k=8*(l>>4)+j], j=0..7.
// wfgp: [30][8 mt][4 kt][64 lane][8]   M=128 (f:0-63, g:64-127), K=128 (k<64: h[t-d] tap0, k>=64: h[t] tap1)
// wrsp: [30][12 mt][2 kt][64 lane][8]  M=192 (r:0-63, s:64-191), K=64
// wpostp/wo1pp: [8 mt][4 kt][64][8]    M=128, K=128
__global__ __launch_bounds__(256) void pack_all(
    const float* __restrict__ Wf, const float* __restrict__ Wg,
    const float* __restrict__ Wr, const float* __restrict__ Ws,
    const float* __restrict__ w_post, const float* __restrict__ w_o1,
    f16* __restrict__ wfgp, f16* __restrict__ wrsp,
    f16* __restrict__ wpostp, f16* __restrict__ wo1pp)
{
    int id = blockIdx.x * 256 + threadIdx.x;
    const int N1 = NLAYERS * 8 * 4 * 64;          // 61440
    const int N2 = NLAYERS * 12 * 2 * 64;         // 46080
    const int N3 = 8 * 4 * 64;                    // 2048
    union { f16 h8[8]; uint4 u; } pk;
    if (id < N1) {
        int l = id & 63, kt = (id >> 6) & 3, mt = (id >> 8) & 7, i = id >> 11;
        int m = mt * 16 + (l & 15);
        int kb = kt * 32 + (l >> 4) * 8;
        #pragma unroll
        for (int j = 0; j < 8; ++j) {
            int k = kb + j, tap = k >> 6, c = k & 63;
            float v = (m < 64) ? Wf[(((i * 64 + m) * 64 + c) << 1) + tap]
                               : Wg[(((i * 64 + m - 64) * 64 + c) << 1) + tap];
            pk.h8[j] = (f16)v;
        }
        *(uint4*)&wfgp[(size_t)id * 8] = pk.u;
    } else if (id < N1 + N2) {
        int id2 = id - N1;
        int l = id2 & 63, kt = (id2 >> 6) & 1, mt = (id2 >> 7) % 12, i = id2 / 1536;
        int m = mt * 16 + (l & 15);
        int cb = kt * 32 + (l >> 4) * 8;
        #pragma unroll
        for (int j = 0; j < 8; ++j) {
            int c = cb + j;
            float v = (m < 64) ? Wr[(i * 64 + m) * 64 + c]
                               : Ws[(i * 128 + m - 64) * 64 + c];
            pk.h8[j] = (f16)v;
        }
        *(uint4*)&wrsp[(size_t)id2 * 8] = pk.u;
    } else if (id < N1 + N2 + 2 * N3) {
        int id3 = id - N1 - N2;
        const float* src = (id3 < N3) ? w_post : w_o1;
        f16* dst = (id3 < N3) ? wpostp : wo1pp;
        int id4 = id3 & (N3 - 1);
        int l = id4 & 63, kt = (id4 >> 6) & 3, mt = (id4 >> 8) & 7;
        int m = mt * 16 + (l & 15);
        int cb = kt * 32 + (l >> 4) * 8;
        #pragma unroll
        for (int j = 0; j < 8; ++j)
            pk.h8[j] = (f16)src[m * 128 + cb + j];
        *(uint4*)&dst[(size_t)id4 * 8] = pk.u;
    }
}

// ---------------- initial causal conv -> h f16 [b][t][64] ----------------
__global__ __launch_bounds__(256) void init_f16(
    const float* __restrict__ x, const float* __restrict__ wc,
    const float* __restrict__ bc, f16* __restrict__ h)
{
    int id = blockIdx.x * 256 + threadIdx.x;      // b*16384 + t
    int t = id & (TLEN - 1);
    float xc = x[id];
    float xp = (t > 0) ? x[id - 1] : 0.f;
    f16* dst = h + (size_t)id * 64;
    #pragma unroll
    for (int c0 = 0; c0 < 64; c0 += 8) {
        union { f16 h8[8]; uint4 u; } pk;
        #pragma unroll
        for (int j = 0; j < 8; ++j) {
            int c = c0 + j;
            pk.h8[j] = (f16)fmaf(wc[2 * c], xp, fmaf(wc[2 * c + 1], xc, bc[c]));
        }
        *(uint4*)&dst[c0] = pk.u;
    }
}

// ---------------- one WaveNet layer, f16 MFMA ----------------
// block: 256 thr = 4 waves; each wave owns 16 t-cols of a 64-t tile. No barriers.
__global__ __launch_bounds__(256, 4) void layer_mfma(
    const f16* __restrict__ hin, f16* __restrict__ hout, f16* __restrict__ skipw,
    const f16* __restrict__ wfgp, const f16* __restrict__ wrsp,
    const float* __restrict__ bf, const float* __restrict__ bg,
    const float* __restrict__ br, const float* __restrict__ bs,
    int layer, int dil, int first)
{
    __shared__ f16 outT[64 * 72];   // [t][o] gated output, row stride 72 (2-way banks only)
    int tid = threadIdx.x, lane = tid & 63, wv = tid >> 6;
    int kg = lane >> 4, ln = lane & 15;
    int bx = blockIdx.x, b = bx >> 8, t0 = (bx & 255) * 64;
    int trow = wv * 16 + ln;                       // 0..63 in tile
    int tl = t0 + trow;                            // global t
    const f16* hb = hin + (size_t)b * TLEN * 64;

    // B-frags for GEMM1: k<64 -> h[t-dil] (c=k), k>=64 -> h[t] (c=k-64)
    f16x8 bf1[4];
    int tprev = tl - dil;
    int tp = tprev < 0 ? 0 : tprev;
    #pragma unroll
    for (int kt = 0; kt < 4; ++kt) {
        int cb = (kt & 1) * 32 + kg * 8;
        int ts = (kt < 2) ? tp : tl;
        f16x8 v = *(const f16x8*)&hb[(size_t)ts * 64 + cb];
        if (kt < 2 && tprev < 0) v = (f16x8){};
        bf1[kt] = v;
    }

    // GEMM1: [128 out x 16 t], K=128
    const f16* wl = wfgp + (size_t)layer * 32 * 64 * 8;
    f32x4 acc[8];
    #pragma unroll
    for (int mt = 0; mt < 8; ++mt) {
        const float* bp = (mt < 4) ? (bf + layer * 64 + mt * 16 + kg * 4)
                                   : (bg + layer * 64 + (mt - 4) * 16 + kg * 4);
        float4 bv = *(const float4*)bp;
        acc[mt] = (f32x4){bv.x, bv.y, bv.z, bv.w};
    }
    #pragma unroll
    for (int mt = 0; mt < 8; ++mt)
        #pragma unroll
        for (int kt = 0; kt < 4; ++kt) {
            f16x8 a = *(const f16x8*)&wl[(size_t)((mt * 4 + kt) * 64 + lane) * 8];
            acc[mt] = __builtin_amdgcn_mfma_f32_16x16x32_f16(a, bf1[kt], acc[mt], 0, 0, 0);
        }

    // gated activation -> f16 -> LDS rows owned by this wave (D: o = mt*16 + kg*4 + reg)
    #pragma unroll
    for (int mt = 0; mt < 4; ++mt) {
        union { f16 h[4]; uint2 u; } pk;
        #pragma unroll
        for (int r = 0; r < 4; ++r) {
            float fv = acc[mt][r], gv = acc[mt + 4][r];
            float e2 = __expf(2.f * fv);
            float th = 1.f - 2.f * __builtin_amdgcn_rcpf(e2 + 1.f);
            float sg = __builtin_amdgcn_rcpf(1.f + __expf(-gv));
            pk.h[r] = (f16)(th * sg);
        }
        *(uint2*)&outT[trow * 72 + mt * 16 + kg * 4] = pk.u;
    }

    // B-frags for GEMM2 from LDS (same rows this wave just wrote; lgkmcnt auto)
    f16x8 bf2[2];
    #pragma unroll
    for (int kt = 0; kt < 2; ++kt)
        bf2[kt] = *(const f16x8*)&outT[trow * 72 + kt * 32 + kg * 8];

    // GEMM2: [192 out x 16 t], K=64  (r: mt 0-3, s: mt 4-11)
    const f16* wl2 = wrsp + (size_t)layer * 24 * 64 * 8;
    f32x4 acc2[12];
    #pragma unroll
    for (int mt = 0; mt < 12; ++mt) {
        const float* bp = (mt < 4) ? (br + layer * 64 + mt * 16 + kg * 4)
                                   : (bs + layer * 128 + (mt - 4) * 16 + kg * 4);
        float4 bv = *(const float4*)bp;
        acc2[mt] = (f32x4){bv.x, bv.y, bv.z, bv.w};
    }
    #pragma unroll
    for (int mt = 0; mt < 12; ++mt)
        #pragma unroll
        for (int kt = 0; kt < 2; ++kt) {
            f16x8 a = *(const f16x8*)&wl2[(size_t)((mt * 2 + kt) * 64 + lane) * 8];
            acc2[mt] = __builtin_amdgcn_mfma_f32_16x16x32_f16(a, bf2[kt], acc2[mt], 0, 0, 0);
        }

    // epilogue: residual h_out = r + h_in  (fp32 add, f16 store)
    #pragma unroll
    for (int mt = 0; mt < 4; ++mt) {
        int o = mt * 16 + kg * 4;
        union { f16 h[4]; uint2 u; } hold, hnew;
        hold.u = *(const uint2*)&hb[(size_t)tl * 64 + o];
        #pragma unroll
        for (int r = 0; r < 4; ++r)
            hnew.h[r] = (f16)(acc2[mt][r] + (float)hold.h[r]);
        *(uint2*)&hout[((size_t)b * TLEN + tl) * 64 + o] = hnew.u;
    }
    // skip accumulate (f16 storage, fp32 add)
    f16* sb = skipw + (size_t)b * TLEN * 128;
    #pragma unroll
    for (int mt = 4; mt < 12; ++mt) {
        int o = (mt - 4) * 16 + kg * 4;
        union { f16 h[4]; uint2 u; } sv;
        if (first) {
            #pragma unroll
            for (int r = 0; r < 4; ++r) sv.h[r] = (f16)acc2[mt][r];
        } else {
            union { f16 h[4]; uint2 u; } old;
            old.u = *(const uint2*)&sb[(size_t)tl * 128 + o];
            #pragma unroll
            for (int r = 0; r < 4; ++r) sv.h[r] = (f16)(acc2[mt][r] + (float)old.h[r]);
        }
        *(uint2*)&sb[(size_t)tl * 128 + o] = sv.u;
    }
}

// ---------------- head: relu(post) -> relu(o1) -> o2, f16 MFMA ----------------
__global__ __launch_bounds__(256, 4) void head_mfma(
    const f16* __restrict__ skipw, const f16* __restrict__ wpostp,
    const f16* __restrict__ wo1pp, const float* __restrict__ wo2,
    const float* __restrict__ b_post, const float* __restrict__ b_o1,
    const float* __restrict__ b_o2, float* __restrict__ out)
{
    __shared__ f16 sT[64 * 136];   // [t][128] relu(post) tile, padded stride
    int tid = threadIdx.x, lane = tid & 63, wv = tid >> 6;
    int kg = lane >> 4, ln = lane & 15;
    int bx = blockIdx.x, b = bx >> 8, t0 = (bx & 255) * 64;
    int trow = wv * 16 + ln;
    int tl = t0 + trow;
    const f16* sb = skipw + (size_t)b * TLEN * 128;

    // GEMM A: s1 = relu(w_post @ skip + b_post)
    f16x8 bfr[4];
    #pragma unroll
    for (int kt = 0; kt < 4; ++kt)
        bfr[kt] = *(const f16x8*)&sb[(size_t)tl * 128 + kt * 32 + kg * 8];
    f32x4 acc[8];
    #pragma unroll
    for (int mt = 0; mt < 8; ++mt) {
        float4 bv = *(const float4*)(b_post + mt * 16 + kg * 4);
        acc[mt] = (f32x4){bv.x, bv.y, bv.z, bv.w};
    }
    #pragma unroll
    for (int mt = 0; mt < 8; ++mt)
        #pragma unroll
        for (int kt = 0; kt < 4; ++kt) {
            f16x8 a = *(const f16x8*)&wpostp[(size_t)((mt * 4 + kt) * 64 + lane) * 8];
            acc[mt] = __builtin_amdgcn_mfma_f32_16x16x32_f16(a, bfr[kt], acc[mt], 0, 0, 0);
        }
    #pragma unroll
    for (int mt = 0; mt < 8; ++mt) {
        union { f16 h[4]; uint2 u; } pk;
        #pragma unroll
        for (int r = 0; r < 4; ++r)
            pk.h[r] = (f16)fmaxf(acc[mt][r], 0.f);
        *(uint2*)&sT[trow * 136 + mt * 16 + kg * 4] = pk.u;
    }

    // GEMM B: s2 = relu(w_o1 @ s1 + b_o1)
    f16x8 b2[4];
    #pragma unroll
    for (int kt = 0; kt < 4; ++kt)
        b2[kt] = *(const f16x8*)&sT[trow * 136 + kt * 32 + kg * 8];
    f32x4 acc2[8];
    #pragma unroll
    for (int mt = 0; mt < 8; ++mt) {
        float4 bv = *(const float4*)(b_o1 + mt * 16 + kg * 4);
        acc2[mt] = (f32x4){bv.x, bv.y, bv.z, bv.w};
    }
    #pragma unroll
    for (int mt = 0; mt < 8; ++mt)
        #pragma unroll
        for (int kt = 0; kt < 4; ++kt) {
            f16x8 a = *(const f16x8*)&wo1pp[(size_t)((mt * 4 + kt) * 64 + lane) * 8];
            acc2[mt] = __builtin_amdgcn_mfma_f32_16x16x32_f16(a, b2[kt], acc2[mt], 0, 0, 0);
        }

    // final 1x1: out[t] = sum_o wo2[o]*relu(s2[o][t]) + b_o2
    float part = 0.f;
    #pragma unroll
    for (int mt = 0; mt < 8; ++mt) {
        float4 wv4 = *(const float4*)(wo2 + mt * 16 + kg * 4);
        part = fmaf(wv4.x, fmaxf(acc2[mt][0], 0.f), part);
        part = fmaf(wv4.y, fmaxf(acc2[mt][1], 0.f), part);
        part = fmaf(wv4.z, fmaxf(acc2[mt][2], 0.f), part);
        part = fmaf(wv4.w, fmaxf(acc2[mt][3], 0.f), part);
    }
    part += __shfl_xor(part, 16);
    part += __shfl_xor(part, 32);
    if (lane < 16)
        out[(size_t)b * TLEN + tl] = part + b_o2[0];
}

// ---------------- host ----------------
extern "C" void kernel_launch(void* const* d_in, const int* in_sizes, int n_in,
                              void* d_out, int out_size, void* d_ws, size_t ws_size,
                              hipStream_t stream) {
    const float* x        = (const float*)d_in[0];
    const float* w_causal = (const float*)d_in[1];
    const float* b_causal = (const float*)d_in[2];
    const float* Wf       = (const float*)d_in[3];
    const float* bf       = (const float*)d_in[4];
    const float* Wg       = (const float*)d_in[5];
    const float* bg       = (const float*)d_in[6];
    const float* Wr       = (const float*)d_in[7];
    const float* br       = (const float*)d_in[8];
    const float* Ws       = (const float*)d_in[9];
    const float* bs       = (const float*)d_in[10];
    const float* w_post   = (const float*)d_in[11];
    const float* b_post   = (const float*)d_in[12];
    const float* w_o1     = (const float*)d_in[13];
    const float* b_o1     = (const float*)d_in[14];
    const float* w_o2     = (const float*)d_in[15];
    const float* b_o2     = (const float*)d_in[16];

    f16* p     = (f16*)d_ws;
    f16* h0    = p;  p += (size_t)NB * TLEN * 64;     // 4.19M
    f16* h1    = p;  p += (size_t)NB * TLEN * 64;
    f16* skipw = p;  p += (size_t)NB * TLEN * 128;    // 8.39M
    f16* wfgp  = p;  p += (size_t)NLAYERS * 8 * 4 * 64 * 8;
    f16* wrsp  = p;  p += (size_t)NLAYERS * 12 * 2 * 64 * 8;
    f16* wpostp= p;  p += (size_t)8 * 4 * 64 * 8;
    f16* wo1pp = p;

    pack_all<<<436, 256, 0, stream>>>(Wf, Wg, Wr, Ws, w_post, w_o1,
                                      wfgp, wrsp, wpostp, wo1pp);
    init_f16<<<NB * TLEN / 256, 256, 0, stream>>>(x, w_causal, b_causal, h0);

    f16* hin = h0;
    f16* hout = h1;
    for (int i = 0; i < NLAYERS; ++i) {
        int d = 1 << (i % 10);
        layer_mfma<<<1024, 256, 0, stream>>>(hin, hout, skipw, wfgp, wrsp,
                                             bf, bg, br, bs, i, d, i == 0);
        f16* tmp = hin; hin = hout; hout = tmp;
    }
    head_mfma<<<1024, 256, 0, stream>>>(skipw, wpostp, wo1pp, w_o2,
                                        b_post, b_o1, b_o2, (float*)d_out);
}

// Round 8
// 672.728 us; speedup vs baseline: 3.5779x; 1.1862x over previous
//
#include <hip/hip_runtime.h>

#define RCH 64
#define SCH 128
#define NLAYERS 30
#define TLEN 16384
#define NB 4
#define LSTR 72   // f16 row stride for LDS tiles (144 B -> max 2-way bank aliasing)

typedef _Float16 f16;
typedef _Float16 f16x8 __attribute__((ext_vector_type(8)));
typedef float f32x4 __attribute__((ext_vector_type(4)));

// ---------------- pack all weights into per-fragment f16 layout ----------------
// A-frag layout for mfma_f32_16x16x32_f16: lane l carries A[m=(l&15)][k=8*(l>>4)+j], j=0..7.
// wfgp: [30][8 mt][4 kt][64 lane][8]   M=128 (f:0-63, g:64-127), K=128 (k<64: h[t-d] tap0, k>=64: h[t] tap1)
// wrsp: [30][12 mt][2 kt][64 lane][8]  M=192 (r:0-63, s:64-191), K=64
// wpostp/wo1pp: [8 mt][4 kt][64][8]    M=128, K=128
__global__ __launch_bounds__(256) void pack_all(
    const float* __restrict__ Wf, const float* __restrict__ Wg,
    const float* __restrict__ Wr, const float* __restrict__ Ws,
    const float* __restrict__ w_post, const float* __restrict__ w_o1,
    f16* __restrict__ wfgp, f16* __restrict__ wrsp,
    f16* __restrict__ wpostp, f16* __restrict__ wo1pp)
{
    int id = blockIdx.x * 256 + threadIdx.x;
    const int N1 = NLAYERS * 8 * 4 * 64;          // 61440
    const int N2 = NLAYERS * 12 * 2 * 64;         // 46080
    const int N3 = 8 * 4 * 64;                    // 2048
    union { f16 h8[8]; uint4 u; } pk;
    if (id < N1) {
        int l = id & 63, kt = (id >> 6) & 3, mt = (id >> 8) & 7, i = id >> 11;
        int m = mt * 16 + (l & 15);
        int kb = kt * 32 + (l >> 4) * 8;
        #pragma unroll
        for (int j = 0; j < 8; ++j) {
            int k = kb + j, tap = k >> 6, c = k & 63;
            float v = (m < 64) ? Wf[(((i * 64 + m) * 64 + c) << 1) + tap]
                               : Wg[(((i * 64 + m - 64) * 64 + c) << 1) + tap];
            pk.h8[j] = (f16)v;
        }
        *(uint4*)&wfgp[(size_t)id * 8] = pk.u;
    } else if (id < N1 + N2) {
        int id2 = id - N1;
        int l = id2 & 63, kt = (id2 >> 6) & 1, mt = (id2 >> 7) % 12, i = id2 / 1536;
        int m = mt * 16 + (l & 15);
        int cb = kt * 32 + (l >> 4) * 8;
        #pragma unroll
        for (int j = 0; j < 8; ++j) {
            int c = cb + j;
            float v = (m < 64) ? Wr[(i * 64 + m) * 64 + c]
                               : Ws[(i * 128 + m - 64) * 64 + c];
            pk.h8[j] = (f16)v;
        }
        *(uint4*)&wrsp[(size_t)id2 * 8] = pk.u;
    } else if (id < N1 + N2 + 2 * N3) {
        int id3 = id - N1 - N2;
        const float* src = (id3 < N3) ? w_post : w_o1;
        f16* dst = (id3 < N3) ? wpostp : wo1pp;
        int id4 = id3 & (N3 - 1);
        int l = id4 & 63, kt = (id4 >> 6) & 3, mt = (id4 >> 8) & 7;
        int m = mt * 16 + (l & 15);
        int cb = kt * 32 + (l >> 4) * 8;
        #pragma unroll
        for (int j = 0; j < 8; ++j)
            pk.h8[j] = (f16)src[m * 128 + cb + j];
        *(uint4*)&dst[(size_t)id4 * 8] = pk.u;
    }
}

// ---------------- initial causal conv -> h f16 [b][t][64] ----------------
__global__ __launch_bounds__(256) void init_f16(
    const float* __restrict__ x, const float* __restrict__ wc,
    const float* __restrict__ bc, f16* __restrict__ h)
{
    int id = blockIdx.x * 256 + threadIdx.x;      // b*16384 + t
    int t = id & (TLEN - 1);
    float xc = x[id];
    float xp = (t > 0) ? x[id - 1] : 0.f;
    f16* dst = h + (size_t)id * 64;
    #pragma unroll
    for (int c0 = 0; c0 < 64; c0 += 8) {
        union { f16 h8[8]; uint4 u; } pk;
        #pragma unroll
        for (int j = 0; j < 8; ++j) {
            int c = c0 + j;
            pk.h8[j] = (f16)fmaf(wc[2 * c], xp, fmaf(wc[2 * c + 1], xc, bc[c]));
        }
        *(uint4*)&dst[c0] = pk.u;
    }
}

// ---------------- one WaveNet layer, f16 MFMA, M-split across waves ----------------
// 256 thr = 4 waves; block covers a 64-t tile.
// GEMM1: wave wv computes f (mt=wv) and g (mt=wv+4) rows for all 64 t  -> f,g wave-local.
// GEMM2: wave wv computes mt in {3wv..3wv+2} of the 192-row r/s output.
// Per-block weight traffic = exactly the 56 KB weight slice (no per-wave amplification).
__global__ __launch_bounds__(256, 4) void layer_mfma(
    const f16* __restrict__ hin, f16* __restrict__ hout, f16* __restrict__ skipw,
    const f16* __restrict__ wfgp, const f16* __restrict__ wrsp,
    const float* __restrict__ bf, const float* __restrict__ bg,
    const float* __restrict__ br, const float* __restrict__ bs,
    int layer, int dil, int first)
{
    __shared__ f16 hcurT[64 * LSTR];
    __shared__ f16 hprvT[64 * LSTR];
    __shared__ f16 outT [64 * LSTR];
    int tid = threadIdx.x, lane = tid & 63, wv = tid >> 6;
    int kg = lane >> 4, ln = lane & 15;
    int bx = blockIdx.x, b = bx >> 8, t0 = (bx & 255) * 64;
    const f16* hb = hin + (size_t)b * TLEN * 64;

    // ---- stage h[t] and h[t-d] tiles: row = tid>>2, chunks q and q+4 (8 f16 = 16 B each)
    {
        int row = tid >> 2, q = tid & 3;
        const f16* src = hb + (size_t)(t0 + row) * 64;
        *(uint4*)&hcurT[row * LSTR + q * 8]       = *(const uint4*)&src[q * 8];
        *(uint4*)&hcurT[row * LSTR + (q + 4) * 8] = *(const uint4*)&src[(q + 4) * 8];
        int tp = t0 + row - dil;
        if (tp >= 0) {
            const f16* sp = hb + (size_t)tp * 64;
            *(uint4*)&hprvT[row * LSTR + q * 8]       = *(const uint4*)&sp[q * 8];
            *(uint4*)&hprvT[row * LSTR + (q + 4) * 8] = *(const uint4*)&sp[(q + 4) * 8];
        } else {
            uint4 z = make_uint4(0, 0, 0, 0);
            *(uint4*)&hprvT[row * LSTR + q * 8]       = z;
            *(uint4*)&hprvT[row * LSTR + (q + 4) * 8] = z;
        }
    }
    __syncthreads();

    // ---- GEMM1: preload this wave's 8 A-frags (f row-tile wv, g row-tile wv+4)
    const f16* wl = wfgp + (size_t)layer * 32 * 64 * 8;
    f16x8 a0[4], a1[4];
    #pragma unroll
    for (int kt = 0; kt < 4; ++kt) {
        a0[kt] = *(const f16x8*)&wl[(size_t)((wv * 4 + kt) * 64 + lane) * 8];
        a1[kt] = *(const f16x8*)&wl[(size_t)(((wv + 4) * 4 + kt) * 64 + lane) * 8];
    }
    f32x4 af[4], ag[4];
    {
        float4 bvf = *(const float4*)(bf + layer * 64 + wv * 16 + kg * 4);
        float4 bvg = *(const float4*)(bg + layer * 64 + wv * 16 + kg * 4);
        #pragma unroll
        for (int ts = 0; ts < 4; ++ts) {
            af[ts] = (f32x4){bvf.x, bvf.y, bvf.z, bvf.w};
            ag[ts] = (f32x4){bvg.x, bvg.y, bvg.z, bvg.w};
        }
    }
    #pragma unroll
    for (int ts = 0; ts < 4; ++ts) {
        #pragma unroll
        for (int kt = 0; kt < 4; ++kt) {
            const f16* tile = (kt < 2) ? hprvT : hcurT;
            f16x8 bb = *(const f16x8*)&tile[(ts * 16 + ln) * LSTR + (kt & 1) * 32 + kg * 8];
            af[ts] = __builtin_amdgcn_mfma_f32_16x16x32_f16(a0[kt], bb, af[ts], 0, 0, 0);
            ag[ts] = __builtin_amdgcn_mfma_f32_16x16x32_f16(a1[kt], bb, ag[ts], 0, 0, 0);
        }
    }

    // ---- gated activation (f,g wave-local) -> outT[t][o], o = wv*16 + kg*4 + r
    #pragma unroll
    for (int ts = 0; ts < 4; ++ts) {
        union { f16 h[4]; uint2 u; } pk;
        #pragma unroll
        for (int r = 0; r < 4; ++r) {
            float fv = af[ts][r], gv = ag[ts][r];
            float e2 = __expf(2.f * fv);
            float th = 1.f - 2.f * __builtin_amdgcn_rcpf(e2 + 1.f);
            float sg = __builtin_amdgcn_rcpf(1.f + __expf(-gv));
            pk.h[r] = (f16)(th * sg);
        }
        *(uint2*)&outT[(ts * 16 + ln) * LSTR + wv * 16 + kg * 4] = pk.u;
    }
    __syncthreads();

    // ---- GEMM2: wave wv owns mt {3wv..3wv+2} of M=192 (r: mt 0-3, s: mt 4-11)
    const f16* wl2 = wrsp + (size_t)layer * 24 * 64 * 8;
    int mt0 = wv * 3;
    f16x8 a2[3][2];
    #pragma unroll
    for (int m = 0; m < 3; ++m)
        #pragma unroll
        for (int kt = 0; kt < 2; ++kt)
            a2[m][kt] = *(const f16x8*)&wl2[(size_t)(((mt0 + m) * 2 + kt) * 64 + lane) * 8];
    f32x4 ac[3][4];
    #pragma unroll
    for (int m = 0; m < 3; ++m) {
        int mtt = mt0 + m;
        const float* bp = (mtt < 4) ? (br + layer * 64 + mtt * 16 + kg * 4)
                                    : (bs + layer * 128 + (mtt - 4) * 16 + kg * 4);
        float4 bv = *(const float4*)bp;
        #pragma unroll
        for (int ts = 0; ts < 4; ++ts)
            ac[m][ts] = (f32x4){bv.x, bv.y, bv.z, bv.w};
    }
    #pragma unroll
    for (int ts = 0; ts < 4; ++ts) {
        #pragma unroll
        for (int kt = 0; kt < 2; ++kt) {
            f16x8 bb = *(const f16x8*)&outT[(ts * 16 + ln) * LSTR + kt * 32 + kg * 8];
            #pragma unroll
            for (int m = 0; m < 3; ++m)
                ac[m][ts] = __builtin_amdgcn_mfma_f32_16x16x32_f16(a2[m][kt], bb, ac[m][ts], 0, 0, 0);
        }
    }

    // ---- epilogue: residual rows (mt<4) from LDS h; skip rows (mt>=4) RMW global
    f16* sb = skipw + (size_t)b * TLEN * 128;
    #pragma unroll
    for (int m = 0; m < 3; ++m) {
        int mtt = mt0 + m;
        if (mtt < 4) {
            int o = mtt * 16 + kg * 4;
            #pragma unroll
            for (int ts = 0; ts < 4; ++ts) {
                int t = ts * 16 + ln;
                union { f16 h[4]; uint2 u; } ho, hn;
                ho.u = *(const uint2*)&hcurT[t * LSTR + o];
                #pragma unroll
                for (int r = 0; r < 4; ++r)
                    hn.h[r] = (f16)(ac[m][ts][r] + (float)ho.h[r]);
                *(uint2*)&hout[((size_t)b * TLEN + t0 + t) * 64 + o] = hn.u;
            }
        } else {
            int oc = (mtt - 4) * 16 + kg * 4;
            #pragma unroll
            for (int ts = 0; ts < 4; ++ts) {
                int t = ts * 16 + ln;
                union { f16 h[4]; uint2 u; } sv;
                if (first) {
                    #pragma unroll
                    for (int r = 0; r < 4; ++r) sv.h[r] = (f16)ac[m][ts][r];
                } else {
                    union { f16 h[4]; uint2 u; } old;
                    old.u = *(const uint2*)&sb[(size_t)(t0 + t) * 128 + oc];
                    #pragma unroll
                    for (int r = 0; r < 4; ++r)
                        sv.h[r] = (f16)(ac[m][ts][r] + (float)old.h[r]);
                }
                *(uint2*)&sb[(size_t)(t0 + t) * 128 + oc] = sv.u;
            }
        }
    }
}

// ---------------- head: relu(post) -> relu(o1) -> o2, f16 MFMA ----------------
__global__ __launch_bounds__(256, 4) void head_mfma(
    const f16* __restrict__ skipw, const f16* __restrict__ wpostp,
    const f16* __restrict__ wo1pp, const float* __restrict__ wo2,
    const float* __restrict__ b_post, const float* __restrict__ b_o1,
    const float* __restrict__ b_o2, float* __restrict__ out)
{
    __shared__ f16 sT[64 * 136];   // [t][128] relu(post) tile, padded stride
    int tid = threadIdx.x, lane = tid & 63, wv = tid >> 6;
    int kg = lane >> 4, ln = lane & 15;
    int bx = blockIdx.x, b = bx >> 8, t0 = (bx & 255) * 64;
    int trow = wv * 16 + ln;
    int tl = t0 + trow;
    const f16* sb = skipw + (size_t)b * TLEN * 128;

    // GEMM A: s1 = relu(w_post @ skip + b_post)
    f16x8 bfr[4];
    #pragma unroll
    for (int kt = 0; kt < 4; ++kt)
        bfr[kt] = *(const f16x8*)&sb[(size_t)tl * 128 + kt * 32 + kg * 8];
    f32x4 acc[8];
    #pragma unroll
    for (int mt = 0; mt < 8; ++mt) {
        float4 bv = *(const float4*)(b_post + mt * 16 + kg * 4);
        acc[mt] = (f32x4){bv.x, bv.y, bv.z, bv.w};
    }
    #pragma unroll
    for (int mt = 0; mt < 8; ++mt)
        #pragma unroll
        for (int kt = 0; kt < 4; ++kt) {
            f16x8 a = *(const f16x8*)&wpostp[(size_t)((mt * 4 + kt) * 64 + lane) * 8];
            acc[mt] = __builtin_amdgcn_mfma_f32_16x16x32_f16(a, bfr[kt], acc[mt], 0, 0, 0);
        }
    #pragma unroll
    for (int mt = 0; mt < 8; ++mt) {
        union { f16 h[4]; uint2 u; } pk;
        #pragma unroll
        for (int r = 0; r < 4; ++r)
            pk.h[r] = (f16)fmaxf(acc[mt][r], 0.f);
        *(uint2*)&sT[trow * 136 + mt * 16 + kg * 4] = pk.u;
    }

    // GEMM B: s2 = relu(w_o1 @ s1 + b_o1)
    f16x8 b2[4];
    #pragma unroll
    for (int kt = 0; kt < 4; ++kt)
        b2[kt] = *(const f16x8*)&sT[trow * 136 + kt * 32 + kg * 8];
    f32x4 acc2[8];
    #pragma unroll
    for (int mt = 0; mt < 8; ++mt) {
        float4 bv = *(const float4*)(b_o1 + mt * 16 + kg * 4);
        acc2[mt] = (f32x4){bv.x, bv.y, bv.z, bv.w};
    }
    #pragma unroll
    for (int mt = 0; mt < 8; ++mt)
        #pragma unroll
        for (int kt = 0; kt < 4; ++kt) {
            f16x8 a = *(const f16x8*)&wo1pp[(size_t)((mt * 4 + kt) * 64 + lane) * 8];
            acc2[mt] = __builtin_amdgcn_mfma_f32_16x16x32_f16(a, b2[kt], acc2[mt], 0, 0, 0);
        }

    // final 1x1: out[t] = sum_o wo2[o]*relu(s2[o][t]) + b_o2
    float part = 0.f;
    #pragma unroll
    for (int mt = 0; mt < 8; ++mt) {
        float4 wv4 = *(const float4*)(wo2 + mt * 16 + kg * 4);
        part = fmaf(wv4.x, fmaxf(acc2[mt][0], 0.f), part);
        part = fmaf(wv4.y, fmaxf(acc2[mt][1], 0.f), part);
        part = fmaf(wv4.z, fmaxf(acc2[mt][2], 0.f), part);
        part = fmaf(wv4.w, fmaxf(acc2[mt][3], 0.f), part);
    }
    part += __shfl_xor(part, 16);
    part += __shfl_xor(part, 32);
    if (lane < 16)
        out[(size_t)b * TLEN + tl] = part + b_o2[0];
}

// ---------------- host ----------------
extern "C" void kernel_launch(void* const* d_in, const int* in_sizes, int n_in,
                              void* d_out, int out_size, void* d_ws, size_t ws_size,
                              hipStream_t stream) {
    const float* x        = (const float*)d_in[0];
    const float* w_causal = (const float*)d_in[1];
    const float* b_causal = (const float*)d_in[2];
    const float* Wf       = (const float*)d_in[3];
    const float* bf       = (const float*)d_in[4];
    const float* Wg       = (const float*)d_in[5];
    const float* bg       = (const float*)d_in[6];
    const float* Wr       = (const float*)d_in[7];
    const float* br       = (const float*)d_in[8];
    const float* Ws       = (const float*)d_in[9];
    const float* bs       = (const float*)d_in[10];
    const float* w_post   = (const float*)d_in[11];
    const float* b_post   = (const float*)d_in[12];
    const float* w_o1     = (const float*)d_in[13];
    const float* b_o1     = (const float*)d_in[14];
    const float* w_o2     = (const float*)d_in[15];
    const float* b_o2     = (const float*)d_in[16];

    f16* p     = (f16*)d_ws;
    f16* h0    = p;  p += (size_t)NB * TLEN * 64;
    f16* h1    = p;  p += (size_t)NB * TLEN * 64;
    f16* skipw = p;  p += (size_t)NB * TLEN * 128;
    f16* wfgp  = p;  p += (size_t)NLAYERS * 8 * 4 * 64 * 8;
    f16* wrsp  = p;  p += (size_t)NLAYERS * 12 * 2 * 64 * 8;
    f16* wpostp= p;  p += (size_t)8 * 4 * 64 * 8;
    f16* wo1pp = p;

    pack_all<<<436, 256, 0, stream>>>(Wf, Wg, Wr, Ws, w_post, w_o1,
                                      wfgp, wrsp, wpostp, wo1pp);
    init_f16<<<NB * TLEN / 256, 256, 0, stream>>>(x, w_causal, b_causal, h0);

    f16* hin = h0;
    f16* hout = h1;
    for (int i = 0; i < NLAYERS; ++i) {
        int d = 1 << (i % 10);
        layer_mfma<<<1024, 256, 0, stream>>>(hin, hout, skipw, wfgp, wrsp,
                                             bf, bg, br, bs, i, d, i == 0);
        f16* tmp = hin; hin = hout; hout = tmp;
    }
    head_mfma<<<1024, 256, 0, stream>>>(skipw, wpostp, wo1pp, w_o2,
                                        b_post, b_o1, b_o2, (float*)d_out);
}

// Round 9
// 645.469 us; speedup vs baseline: 3.7290x; 1.0422x over previous
//
#include <hip/hip_runtime.h>

#define RCH 64
#define SCH 128
#define NLAYERS 30
#define TLEN 16384
#define NB 4
#define LSTR 72   // f16 row stride for LDS tiles

typedef _Float16 f16;
typedef _Float16 f16x8 __attribute__((ext_vector_type(8)));
typedef float f32x4 __attribute__((ext_vector_type(4)));

// ---------------- pack all weights into per-fragment f16 layout ----------------
// A-frag: lane l carries A[m=(l&15)][k=8*(l>>4)+j], j=0..7.
// wfgp: [30][8 mt][4 kt][64][8]   M=128 (f,g), K=128 (kt0/1: h[t-d] c0-63, kt2/3: h[t] c0-63)
// wrsp: [30][12 mt][2 kt][64][8]  M=192 (r 0-63, s 64-191), K=64
// wpostp/wo1pp: [8 mt][4 kt][64][8]
__global__ __launch_bounds__(256) void pack_all(
    const float* __restrict__ Wf, const float* __restrict__ Wg,
    const float* __restrict__ Wr, const float* __restrict__ Ws,
    const float* __restrict__ w_post, const float* __restrict__ w_o1,
    f16* __restrict__ wfgp, f16* __restrict__ wrsp,
    f16* __restrict__ wpostp, f16* __restrict__ wo1pp)
{
    int id = blockIdx.x * 256 + threadIdx.x;
    const int N1 = NLAYERS * 8 * 4 * 64;
    const int N2 = NLAYERS * 12 * 2 * 64;
    const int N3 = 8 * 4 * 64;
    union { f16 h8[8]; uint4 u; } pk;
    if (id < N1) {
        int l = id & 63, kt = (id >> 6) & 3, mt = (id >> 8) & 7, i = id >> 11;
        int m = mt * 16 + (l & 15);
        int kb = kt * 32 + (l >> 4) * 8;
        #pragma unroll
        for (int j = 0; j < 8; ++j) {
            int k = kb + j, tap = k >> 6, c = k & 63;
            float v = (m < 64) ? Wf[(((i * 64 + m) * 64 + c) << 1) + tap]
                               : Wg[(((i * 64 + m - 64) * 64 + c) << 1) + tap];
            pk.h8[j] = (f16)v;
        }
        *(uint4*)&wfgp[(size_t)id * 8] = pk.u;
    } else if (id < N1 + N2) {
        int id2 = id - N1;
        int l = id2 & 63, kt = (id2 >> 6) & 1, mt = (id2 >> 7) % 12, i = id2 / 1536;
        int m = mt * 16 + (l & 15);
        int cb = kt * 32 + (l >> 4) * 8;
        #pragma unroll
        for (int j = 0; j < 8; ++j) {
            int c = cb + j;
            float v = (m < 64) ? Wr[(i * 64 + m) * 64 + c]
                               : Ws[(i * 128 + m - 64) * 64 + c];
            pk.h8[j] = (f16)v;
        }
        *(uint4*)&wrsp[(size_t)id2 * 8] = pk.u;
    } else if (id < N1 + N2 + 2 * N3) {
        int id3 = id - N1 - N2;
        const float* src = (id3 < N3) ? w_post : w_o1;
        f16* dst = (id3 < N3) ? wpostp : wo1pp;
        int id4 = id3 & (N3 - 1);
        int l = id4 & 63, kt = (id4 >> 6) & 3, mt = (id4 >> 8) & 7;
        int m = mt * 16 + (l & 15);
        int cb = kt * 32 + (l >> 4) * 8;
        #pragma unroll
        for (int j = 0; j < 8; ++j)
            pk.h8[j] = (f16)src[m * 128 + cb + j];
        *(uint4*)&dst[(size_t)id4 * 8] = pk.u;
    }
}

// ---------------- initial causal conv -> h f16 [b][t][64] ----------------
__global__ __launch_bounds__(256) void init_f16(
    const float* __restrict__ x, const float* __restrict__ wc,
    const float* __restrict__ bc, f16* __restrict__ h)
{
    int id = blockIdx.x * 256 + threadIdx.x;
    int t = id & (TLEN - 1);
    float xc = x[id];
    float xp = (t > 0) ? x[id - 1] : 0.f;
    f16* dst = h + (size_t)id * 64;
    #pragma unroll
    for (int c0 = 0; c0 < 64; c0 += 8) {
        union { f16 h8[8]; uint4 u; } pk;
        #pragma unroll
        for (int j = 0; j < 8; ++j) {
            int c = c0 + j;
            pk.h8[j] = (f16)fmaf(wc[2 * c], xp, fmaf(wc[2 * c + 1], xc, bc[c]));
        }
        *(uint4*)&dst[c0] = pk.u;
    }
}

// ---------------- one WaveNet layer: f16 MFMA, M-split, coalesced epilogue ----------------
__global__ __launch_bounds__(256, 4) void layer_mfma(
    const f16* __restrict__ hin, f16* __restrict__ hout, f16* __restrict__ skipw,
    const f16* __restrict__ wfgp, const f16* __restrict__ wrsp,
    const float* __restrict__ bf, const float* __restrict__ bg,
    const float* __restrict__ br, const float* __restrict__ bs,
    int layer, int dil, int first)
{
    __shared__ f16 hcurT[64 * LSTR];
    __shared__ f16 hprvT[64 * LSTR];   // after GEMM1: reused for h-result
    __shared__ f16 outT [64 * LSTR];   // gated out; after GEMM2: skip-lo increments
    __shared__ f16 extT [64 * LSTR];   // skip-hi increments
    int tid = threadIdx.x, lane = tid & 63, wv = tid >> 6;
    int kg = lane >> 4, ln = lane & 15;
    int bx = blockIdx.x, b = bx >> 8, t0 = (bx & 255) * 64;
    const f16* hb = hin + (size_t)b * TLEN * 64;
    f16* sb = skipw + (size_t)b * TLEN * 128;
    int row = tid >> 2, q = tid & 3;

    // ---- early coalesced preload of old skip (64 B/thread, in flight across barriers)
    uint4 sold[4];
    if (!first) {
        const f16* srow = sb + (size_t)(t0 + row) * 128 + q * 32;
        #pragma unroll
        for (int k = 0; k < 4; ++k)
            sold[k] = *(const uint4*)&srow[k * 8];
    }

    // ---- stage h[t] and h[t-d] tiles (coalesced reads, 32 B/thread each tile)
    {
        const f16* src = hb + (size_t)(t0 + row) * 64;
        *(uint4*)&hcurT[row * LSTR + q * 8]       = *(const uint4*)&src[q * 8];
        *(uint4*)&hcurT[row * LSTR + (q + 4) * 8] = *(const uint4*)&src[(q + 4) * 8];
        int tp = t0 + row - dil;
        if (tp >= 0) {
            const f16* sp = hb + (size_t)tp * 64;
            *(uint4*)&hprvT[row * LSTR + q * 8]       = *(const uint4*)&sp[q * 8];
            *(uint4*)&hprvT[row * LSTR + (q + 4) * 8] = *(const uint4*)&sp[(q + 4) * 8];
        } else {
            uint4 z = make_uint4(0, 0, 0, 0);
            *(uint4*)&hprvT[row * LSTR + q * 8]       = z;
            *(uint4*)&hprvT[row * LSTR + (q + 4) * 8] = z;
        }
    }
    __syncthreads();   // (1) staging visible

    // ---- GEMM1: wave wv owns f row-tile wv and g row-tile wv+4
    const f16* wl = wfgp + (size_t)layer * 32 * 64 * 8;
    f16x8 a0[4], a1[4];
    #pragma unroll
    for (int kt = 0; kt < 4; ++kt) {
        a0[kt] = *(const f16x8*)&wl[(size_t)((wv * 4 + kt) * 64 + lane) * 8];
        a1[kt] = *(const f16x8*)&wl[(size_t)(((wv + 4) * 4 + kt) * 64 + lane) * 8];
    }
    f32x4 af[4], ag[4];
    {
        float4 bvf = *(const float4*)(bf + layer * 64 + wv * 16 + kg * 4);
        float4 bvg = *(const float4*)(bg + layer * 64 + wv * 16 + kg * 4);
        #pragma unroll
        for (int ts = 0; ts < 4; ++ts) {
            af[ts] = (f32x4){bvf.x, bvf.y, bvf.z, bvf.w};
            ag[ts] = (f32x4){bvg.x, bvg.y, bvg.z, bvg.w};
        }
    }
    #pragma unroll
    for (int ts = 0; ts < 4; ++ts) {
        #pragma unroll
        for (int kt = 0; kt < 4; ++kt) {
            const f16* tile = (kt < 2) ? hprvT : hcurT;
            f16x8 bb = *(const f16x8*)&tile[(ts * 16 + ln) * LSTR + (kt & 1) * 32 + kg * 8];
            af[ts] = __builtin_amdgcn_mfma_f32_16x16x32_f16(a0[kt], bb, af[ts], 0, 0, 0);
            ag[ts] = __builtin_amdgcn_mfma_f32_16x16x32_f16(a1[kt], bb, ag[ts], 0, 0, 0);
        }
    }

    // ---- gated activation -> outT[t][o], o = wv*16 + kg*4 + r  (wave-local rows)
    #pragma unroll
    for (int ts = 0; ts < 4; ++ts) {
        union { f16 h[4]; uint2 u; } pk;
        #pragma unroll
        for (int r = 0; r < 4; ++r) {
            float fv = af[ts][r], gv = ag[ts][r];
            float e2 = __expf(2.f * fv);
            float th = 1.f - 2.f * __builtin_amdgcn_rcpf(e2 + 1.f);
            float sg = __builtin_amdgcn_rcpf(1.f + __expf(-gv));
            pk.h[r] = (f16)(th * sg);
        }
        *(uint2*)&outT[(ts * 16 + ln) * LSTR + wv * 16 + kg * 4] = pk.u;
    }

    // ---- prefetch GEMM2 A-frags (hidden behind activation + barrier)
    const f16* wl2 = wrsp + (size_t)layer * 24 * 64 * 8;
    int mt0 = wv * 3;
    f16x8 a2[3][2];
    #pragma unroll
    for (int m = 0; m < 3; ++m)
        #pragma unroll
        for (int kt = 0; kt < 2; ++kt)
            a2[m][kt] = *(const f16x8*)&wl2[(size_t)(((mt0 + m) * 2 + kt) * 64 + lane) * 8];
    __syncthreads();   // (2) outT visible

    // ---- GEMM2: wave wv owns mt {3wv..3wv+2} of M=192
    f32x4 ac[3][4];
    #pragma unroll
    for (int m = 0; m < 3; ++m) {
        int mtt = mt0 + m;
        const float* bp = (mtt < 4) ? (br + layer * 64 + mtt * 16 + kg * 4)
                                    : (bs + layer * 128 + (mtt - 4) * 16 + kg * 4);
        float4 bv = *(const float4*)bp;
        #pragma unroll
        for (int ts = 0; ts < 4; ++ts)
            ac[m][ts] = (f32x4){bv.x, bv.y, bv.z, bv.w};
    }
    #pragma unroll
    for (int ts = 0; ts < 4; ++ts) {
        #pragma unroll
        for (int kt = 0; kt < 2; ++kt) {
            f16x8 bb = *(const f16x8*)&outT[(ts * 16 + ln) * LSTR + kt * 32 + kg * 8];
            #pragma unroll
            for (int m = 0; m < 3; ++m)
                ac[m][ts] = __builtin_amdgcn_mfma_f32_16x16x32_f16(a2[m][kt], bb, ac[m][ts], 0, 0, 0);
        }
    }
    __syncthreads();   // (3) all GEMM2 LDS reads done; tiles reusable

    // ---- scatter results to LDS: h-result -> hprvT, skip-lo -> outT, skip-hi -> extT
    #pragma unroll
    for (int m = 0; m < 3; ++m) {
        int mtt = mt0 + m;
        if (mtt < 4) {
            int o = mtt * 16 + kg * 4;
            #pragma unroll
            for (int ts = 0; ts < 4; ++ts) {
                int t = ts * 16 + ln;
                union { f16 h[4]; uint2 u; } ho, hn;
                ho.u = *(const uint2*)&hcurT[t * LSTR + o];
                #pragma unroll
                for (int r = 0; r < 4; ++r)
                    hn.h[r] = (f16)(ac[m][ts][r] + (float)ho.h[r]);
                *(uint2*)&hprvT[t * LSTR + o] = hn.u;
            }
        } else {
            f16* dstT = (mtt < 8) ? outT : extT;
            int ch = ((mtt - 4) & 3) * 16 + kg * 4;
            #pragma unroll
            for (int ts = 0; ts < 4; ++ts) {
                int t = ts * 16 + ln;
                union { f16 h[4]; uint2 u; } sv;
                #pragma unroll
                for (int r = 0; r < 4; ++r) sv.h[r] = (f16)ac[m][ts][r];
                *(uint2*)&dstT[t * LSTR + ch] = sv.u;
            }
        }
    }
    __syncthreads();   // (4) scatter visible

    // ---- coalesced global phase
    // h: thread covers 32 B of row `row` at ch q*16
    {
        f16* hrow = hout + ((size_t)b * TLEN + t0 + row) * 64 + q * 16;
        *(uint4*)&hrow[0] = *(const uint4*)&hprvT[row * LSTR + q * 16];
        *(uint4*)&hrow[8] = *(const uint4*)&hprvT[row * LSTR + q * 16 + 8];
    }
    // skip: thread covers 64 B of row `row` at ch q*32 (q<2 -> lo buf, q>=2 -> hi buf)
    {
        f16* drow = sb + (size_t)(t0 + row) * 128 + q * 32;
        const f16* incb = ((q < 2) ? outT : extT) + row * LSTR + (q & 1) * 32;
        if (first) {
            #pragma unroll
            for (int k = 0; k < 4; ++k)
                *(uint4*)&drow[k * 8] = *(const uint4*)&incb[k * 8];
        } else {
            #pragma unroll
            for (int k = 0; k < 4; ++k) {
                union { f16 h[8]; uint4 u; } o_, i_, n_;
                o_.u = sold[k];
                i_.u = *(const uint4*)&incb[k * 8];
                #pragma unroll
                for (int j = 0; j < 8; ++j)
                    n_.h[j] = (f16)((float)o_.h[j] + (float)i_.h[j]);
                *(uint4*)&drow[k * 8] = n_.u;
            }
        }
    }
}

// ---------------- head: relu(post) -> relu(o1) -> o2, f16 MFMA ----------------
__global__ __launch_bounds__(256, 4) void head_mfma(
    const f16* __restrict__ skipw, const f16* __restrict__ wpostp,
    const f16* __restrict__ wo1pp, const float* __restrict__ wo2,
    const float* __restrict__ b_post, const float* __restrict__ b_o1,
    const float* __restrict__ b_o2, float* __restrict__ out)
{
    __shared__ f16 sT[64 * 136];
    int tid = threadIdx.x, lane = tid & 63, wv = tid >> 6;
    int kg = lane >> 4, ln = lane & 15;
    int bx = blockIdx.x, b = bx >> 8, t0 = (bx & 255) * 64;
    int trow = wv * 16 + ln;
    int tl = t0 + trow;
    const f16* sb = skipw + (size_t)b * TLEN * 128;

    f16x8 bfr[4];
    #pragma unroll
    for (int kt = 0; kt < 4; ++kt)
        bfr[kt] = *(const f16x8*)&sb[(size_t)tl * 128 + kt * 32 + kg * 8];
    f32x4 acc[8];
    #pragma unroll
    for (int mt = 0; mt < 8; ++mt) {
        float4 bv = *(const float4*)(b_post + mt * 16 + kg * 4);
        acc[mt] = (f32x4){bv.x, bv.y, bv.z, bv.w};
    }
    #pragma unroll
    for (int mt = 0; mt < 8; ++mt)
        #pragma unroll
        for (int kt = 0; kt < 4; ++kt) {
            f16x8 a = *(const f16x8*)&wpostp[(size_t)((mt * 4 + kt) * 64 + lane) * 8];
            acc[mt] = __builtin_amdgcn_mfma_f32_16x16x32_f16(a, bfr[kt], acc[mt], 0, 0, 0);
        }
    #pragma unroll
    for (int mt = 0; mt < 8; ++mt) {
        union { f16 h[4]; uint2 u; } pk;
        #pragma unroll
        for (int r = 0; r < 4; ++r)
            pk.h[r] = (f16)fmaxf(acc[mt][r], 0.f);
        *(uint2*)&sT[trow * 136 + mt * 16 + kg * 4] = pk.u;
    }

    f16x8 b2[4];
    #pragma unroll
    for (int kt = 0; kt < 4; ++kt)
        b2[kt] = *(const f16x8*)&sT[trow * 136 + kt * 32 + kg * 8];
    f32x4 acc2[8];
    #pragma unroll
    for (int mt = 0; mt < 8; ++mt) {
        float4 bv = *(const float4*)(b_o1 + mt * 16 + kg * 4);
        acc2[mt] = (f32x4){bv.x, bv.y, bv.z, bv.w};
    }
    #pragma unroll
    for (int mt = 0; mt < 8; ++mt)
        #pragma unroll
        for (int kt = 0; kt < 4; ++kt) {
            f16x8 a = *(const f16x8*)&wo1pp[(size_t)((mt * 4 + kt) * 64 + lane) * 8];
            acc2[mt] = __builtin_amdgcn_mfma_f32_16x16x32_f16(a, b2[kt], acc2[mt], 0, 0, 0);
        }

    float part = 0.f;
    #pragma unroll
    for (int mt = 0; mt < 8; ++mt) {
        float4 wv4 = *(const float4*)(wo2 + mt * 16 + kg * 4);
        part = fmaf(wv4.x, fmaxf(acc2[mt][0], 0.f), part);
        part = fmaf(wv4.y, fmaxf(acc2[mt][1], 0.f), part);
        part = fmaf(wv4.z, fmaxf(acc2[mt][2], 0.f), part);
        part = fmaf(wv4.w, fmaxf(acc2[mt][3], 0.f), part);
    }
    part += __shfl_xor(part, 16);
    part += __shfl_xor(part, 32);
    if (lane < 16)
        out[(size_t)b * TLEN + tl] = part + b_o2[0];
}

// ---------------- host ----------------
extern "C" void kernel_launch(void* const* d_in, const int* in_sizes, int n_in,
                              void* d_out, int out_size, void* d_ws, size_t ws_size,
                              hipStream_t stream) {
    const float* x        = (const float*)d_in[0];
    const float* w_causal = (const float*)d_in[1];
    const float* b_causal = (const float*)d_in[2];
    const float* Wf       = (const float*)d_in[3];
    const float* bf       = (const float*)d_in[4];
    const float* Wg       = (const float*)d_in[5];
    const float* bg       = (const float*)d_in[6];
    const float* Wr       = (const float*)d_in[7];
    const float* br       = (const float*)d_in[8];
    const float* Ws       = (const float*)d_in[9];
    const float* bs       = (const float*)d_in[10];
    const float* w_post   = (const float*)d_in[11];
    const float* b_post   = (const float*)d_in[12];
    const float* w_o1     = (const float*)d_in[13];
    const float* b_o1     = (const float*)d_in[14];
    const float* w_o2     = (const float*)d_in[15];
    const float* b_o2     = (const float*)d_in[16];

    f16* p     = (f16*)d_ws;
    f16* h0    = p;  p += (size_t)NB * TLEN * 64;
    f16* h1    = p;  p += (size_t)NB * TLEN * 64;
    f16* skipw = p;  p += (size_t)NB * TLEN * 128;
    f16* wfgp  = p;  p += (size_t)NLAYERS * 8 * 4 * 64 * 8;
    f16* wrsp  = p;  p += (size_t)NLAYERS * 12 * 2 * 64 * 8;
    f16* wpostp= p;  p += (size_t)8 * 4 * 64 * 8;
    f16* wo1pp = p;

    pack_all<<<436, 256, 0, stream>>>(Wf, Wg, Wr, Ws, w_post, w_o1,
                                      wfgp, wrsp, wpostp, wo1pp);
    init_f16<<<NB * TLEN / 256, 256, 0, stream>>>(x, w_causal, b_causal, h0);

    f16* hin = h0;
    f16* hout = h1;
    for (int i = 0; i < NLAYERS; ++i) {
        int d = 1 << (i % 10);
        layer_mfma<<<1024, 256, 0, stream>>>(hin, hout, skipw, wfgp, wrsp,
                                             bf, bg, br, bs, i, d, i == 0);
        f16* tmp = hin; hin = hout; hout = tmp;
    }
    head_mfma<<<1024, 256, 0, stream>>>(skipw, wpostp, wo1pp, w_o2,
                                        b_post, b_o1, b_o2, (float*)d_out);
}

// Round 11
// 616.272 us; speedup vs baseline: 3.9056x; 1.0474x over previous
//
#include <hip/hip_runtime.h>

#define RCH 64
#define SCH 128
#define NLAYERS 30
#define TLEN 16384
#define NB 4
#define LSTR 72   // f16 row stride for LDS tiles

typedef _Float16 f16;
typedef _Float16 f16x8 __attribute__((ext_vector_type(8)));
typedef float f32x4 __attribute__((ext_vector_type(4)));

// ---------------- pack all weights into per-fragment f16 layout ----------------
__global__ __launch_bounds__(256) void pack_all(
    const float* __restrict__ Wf, const float* __restrict__ Wg,
    const float* __restrict__ Wr, const float* __restrict__ Ws,
    const float* __restrict__ w_post, const float* __restrict__ w_o1,
    f16* __restrict__ wfgp, f16* __restrict__ wrsp,
    f16* __restrict__ wpostp, f16* __restrict__ wo1pp)
{
    int id = blockIdx.x * 256 + threadIdx.x;
    const int N1 = NLAYERS * 8 * 4 * 64;
    const int N2 = NLAYERS * 12 * 2 * 64;
    const int N3 = 8 * 4 * 64;
    union { f16 h8[8]; uint4 u; } pk;
    if (id < N1) {
        int l = id & 63, kt = (id >> 6) & 3, mt = (id >> 8) & 7, i = id >> 11;
        int m = mt * 16 + (l & 15);
        int kb = kt * 32 + (l >> 4) * 8;
        #pragma unroll
        for (int j = 0; j < 8; ++j) {
            int k = kb + j, tap = k >> 6, c = k & 63;
            float v = (m < 64) ? Wf[(((i * 64 + m) * 64 + c) << 1) + tap]
                               : Wg[(((i * 64 + m - 64) * 64 + c) << 1) + tap];
            pk.h8[j] = (f16)v;
        }
        *(uint4*)&wfgp[(size_t)id * 8] = pk.u;
    } else if (id < N1 + N2) {
        int id2 = id - N1;
        int l = id2 & 63, kt = (id2 >> 6) & 1, mt = (id2 >> 7) % 12, i = id2 / 1536;
        int m = mt * 16 + (l & 15);
        int cb = kt * 32 + (l >> 4) * 8;
        #pragma unroll
        for (int j = 0; j < 8; ++j) {
            int c = cb + j;
            float v = (m < 64) ? Wr[(i * 64 + m) * 64 + c]
                               : Ws[(i * 128 + m - 64) * 64 + c];
            pk.h8[j] = (f16)v;
        }
        *(uint4*)&wrsp[(size_t)id2 * 8] = pk.u;
    } else if (id < N1 + N2 + 2 * N3) {
        int id3 = id - N1 - N2;
        const float* src = (id3 < N3) ? w_post : w_o1;
        f16* dst = (id3 < N3) ? wpostp : wo1pp;
        int id4 = id3 & (N3 - 1);
        int l = id4 & 63, kt = (id4 >> 6) & 3, mt = (id4 >> 8) & 7;
        int m = mt * 16 + (l & 15);
        int cb = kt * 32 + (l >> 4) * 8;
        #pragma unroll
        for (int j = 0; j < 8; ++j)
            pk.h8[j] = (f16)src[m * 128 + cb + j];
        *(uint4*)&dst[(size_t)id4 * 8] = pk.u;
    }
}

// ---------------- initial causal conv -> h f16 [b][t][64] ----------------
__global__ __launch_bounds__(256) void init_f16(
    const float* __restrict__ x, const float* __restrict__ wc,
    const float* __restrict__ bc, f16* __restrict__ h)
{
    int id = blockIdx.x * 256 + threadIdx.x;
    int t = id & (TLEN - 1);
    float xc = x[id];
    float xp = (t > 0) ? x[id - 1] : 0.f;
    f16* dst = h + (size_t)id * 64;
    #pragma unroll
    for (int c0 = 0; c0 < 64; c0 += 8) {
        union { f16 h8[8]; uint4 u; } pk;
        #pragma unroll
        for (int j = 0; j < 8; ++j) {
            int c = c0 + j;
            pk.h8[j] = (f16)fmaf(wc[2 * c], xp, fmaf(wc[2 * c + 1], xc, bc[c]));
        }
        *(uint4*)&dst[c0] = pk.u;
    }
}

// ---------------- one WaveNet layer: f16 MFMA, M-split, XCD-chunked tiles ----------------
// blockIdx -> tile swizzle: XCD x (= blockIdx%8, HW round-robin) owns contiguous
// tiles [x*128,(x+1)*128). Per-XCD slice = h ping-pong (2 MB) + skip (2 MB) ~= L2 size,
// and the SAME XCD re-touches the SAME slice every layer -> inter-layer traffic is L2-hit.
__global__ __launch_bounds__(256, 4) void layer_mfma(
    const f16* __restrict__ hin, f16* __restrict__ hout, f16* __restrict__ skipw,
    const f16* __restrict__ wfgp, const f16* __restrict__ wrsp,
    const float* __restrict__ bf, const float* __restrict__ bg,
    const float* __restrict__ br, const float* __restrict__ bs,
    int layer, int dil, int first)
{
    __shared__ f16 hcurT[64 * LSTR];
    __shared__ f16 hprvT[64 * LSTR];   // after GEMM1: reused for h-result
    __shared__ f16 outT [64 * LSTR];   // gated out; after GEMM2: skip-lo increments
    __shared__ f16 extT [64 * LSTR];   // skip-hi increments
    int tid = threadIdx.x, lane = tid & 63, wv = tid >> 6;
    int kg = lane >> 4, ln = lane & 15;
    int gt = (blockIdx.x & 7) * 128 + (blockIdx.x >> 3);  // XCD-chunked global tile id
    int b = gt >> 8, t0 = (gt & 255) * 64;
    const f16* hb = hin + (size_t)b * TLEN * 64;
    f16* sb = skipw + (size_t)b * TLEN * 128;
    int row = tid >> 2, q = tid & 3;

    // ---- early coalesced preload of old skip (64 B/thread, in flight across barriers)
    uint4 sold[4];
    if (!first) {
        const f16* srow = sb + (size_t)(t0 + row) * 128 + q * 32;
        #pragma unroll
        for (int k = 0; k < 4; ++k)
            sold[k] = *(const uint4*)&srow[k * 8];
    }

    // ---- stage h[t] and h[t-d] tiles (coalesced reads, 32 B/thread each tile)
    {
        const f16* src = hb + (size_t)(t0 + row) * 64;
        *(uint4*)&hcurT[row * LSTR + q * 8]       = *(const uint4*)&src[q * 8];
        *(uint4*)&hcurT[row * LSTR + (q + 4) * 8] = *(const uint4*)&src[(q + 4) * 8];
        int tp = t0 + row - dil;
        if (tp >= 0) {
            const f16* sp = hb + (size_t)tp * 64;
            *(uint4*)&hprvT[row * LSTR + q * 8]       = *(const uint4*)&sp[q * 8];
            *(uint4*)&hprvT[row * LSTR + (q + 4) * 8] = *(const uint4*)&sp[(q + 4) * 8];
        } else {
            uint4 z = make_uint4(0, 0, 0, 0);
            *(uint4*)&hprvT[row * LSTR + q * 8]       = z;
            *(uint4*)&hprvT[row * LSTR + (q + 4) * 8] = z;
        }
    }
    __syncthreads();   // (1) staging visible

    // ---- GEMM1: wave wv owns f row-tile wv and g row-tile wv+4
    const f16* wl = wfgp + (size_t)layer * 32 * 64 * 8;
    f16x8 a0[4], a1[4];
    #pragma unroll
    for (int kt = 0; kt < 4; ++kt) {
        a0[kt] = *(const f16x8*)&wl[(size_t)((wv * 4 + kt) * 64 + lane) * 8];
        a1[kt] = *(const f16x8*)&wl[(size_t)(((wv + 4) * 4 + kt) * 64 + lane) * 8];
    }
    f32x4 af[4], ag[4];
    {
        float4 bvf = *(const float4*)(bf + layer * 64 + wv * 16 + kg * 4);
        float4 bvg = *(const float4*)(bg + layer * 64 + wv * 16 + kg * 4);
        #pragma unroll
        for (int ts = 0; ts < 4; ++ts) {
            af[ts] = (f32x4){bvf.x, bvf.y, bvf.z, bvf.w};
            ag[ts] = (f32x4){bvg.x, bvg.y, bvg.z, bvg.w};
        }
    }
    #pragma unroll
    for (int ts = 0; ts < 4; ++ts) {
        #pragma unroll
        for (int kt = 0; kt < 4; ++kt) {
            const f16* tile = (kt < 2) ? hprvT : hcurT;
            f16x8 bb = *(const f16x8*)&tile[(ts * 16 + ln) * LSTR + (kt & 1) * 32 + kg * 8];
            af[ts] = __builtin_amdgcn_mfma_f32_16x16x32_f16(a0[kt], bb, af[ts], 0, 0, 0);
            ag[ts] = __builtin_amdgcn_mfma_f32_16x16x32_f16(a1[kt], bb, ag[ts], 0, 0, 0);
        }
    }

    // ---- gated activation -> outT[t][o], o = wv*16 + kg*4 + r  (wave-local rows)
    #pragma unroll
    for (int ts = 0; ts < 4; ++ts) {
        union { f16 h[4]; uint2 u; } pk;
        #pragma unroll
        for (int r = 0; r < 4; ++r) {
            float fv = af[ts][r], gv = ag[ts][r];
            float e2 = __expf(2.f * fv);
            float th = 1.f - 2.f * __builtin_amdgcn_rcpf(e2 + 1.f);
            float sg = __builtin_amdgcn_rcpf(1.f + __expf(-gv));
            pk.h[r] = (f16)(th * sg);
        }
        *(uint2*)&outT[(ts * 16 + ln) * LSTR + wv * 16 + kg * 4] = pk.u;
    }

    // ---- prefetch GEMM2 A-frags (hidden behind activation + barrier)
    const f16* wl2 = wrsp + (size_t)layer * 24 * 64 * 8;
    int mt0 = wv * 3;
    f16x8 a2[3][2];
    #pragma unroll
    for (int m = 0; m < 3; ++m)
        #pragma unroll
        for (int kt = 0; kt < 2; ++kt)
            a2[m][kt] = *(const f16x8*)&wl2[(size_t)(((mt0 + m) * 2 + kt) * 64 + lane) * 8];
    __syncthreads();   // (2) outT visible

    // ---- GEMM2: wave wv owns mt {3wv..3wv+2} of M=192
    f32x4 ac[3][4];
    #pragma unroll
    for (int m = 0; m < 3; ++m) {
        int mtt = mt0 + m;
        const float* bp = (mtt < 4) ? (br + layer * 64 + mtt * 16 + kg * 4)
                                    : (bs + layer * 128 + (mtt - 4) * 16 + kg * 4);
        float4 bv = *(const float4*)bp;
        #pragma unroll
        for (int ts = 0; ts < 4; ++ts)
            ac[m][ts] = (f32x4){bv.x, bv.y, bv.z, bv.w};
    }
    #pragma unroll
    for (int ts = 0; ts < 4; ++ts) {
        #pragma unroll
        for (int kt = 0; kt < 2; ++kt) {
            f16x8 bb = *(const f16x8*)&outT[(ts * 16 + ln) * LSTR + kt * 32 + kg * 8];
            #pragma unroll
            for (int m = 0; m < 3; ++m)
                ac[m][ts] = __builtin_amdgcn_mfma_f32_16x16x32_f16(a2[m][kt], bb, ac[m][ts], 0, 0, 0);
        }
    }
    __syncthreads();   // (3) all GEMM2 LDS reads done; tiles reusable

    // ---- scatter results to LDS: h-result -> hprvT, skip-lo -> outT, skip-hi -> extT
    #pragma unroll
    for (int m = 0; m < 3; ++m) {
        int mtt = mt0 + m;
        if (mtt < 4) {
            int o = mtt * 16 + kg * 4;
            #pragma unroll
            for (int ts = 0; ts < 4; ++ts) {
                int t = ts * 16 + ln;
                union { f16 h[4]; uint2 u; } ho, hn;
                ho.u = *(const uint2*)&hcurT[t * LSTR + o];
                #pragma unroll
                for (int r = 0; r < 4; ++r)
                    hn.h[r] = (f16)(ac[m][ts][r] + (float)ho.h[r]);
                *(uint2*)&hprvT[t * LSTR + o] = hn.u;
            }
        } else {
            f16* dstT = (mtt < 8) ? outT : extT;
            int ch = ((mtt - 4) & 3) * 16 + kg * 4;
            #pragma unroll
            for (int ts = 0; ts < 4; ++ts) {
                int t = ts * 16 + ln;
                union { f16 h[4]; uint2 u; } sv;
                #pragma unroll
                for (int r = 0; r < 4; ++r) sv.h[r] = (f16)ac[m][ts][r];
                *(uint2*)&dstT[t * LSTR + ch] = sv.u;
            }
        }
    }
    __syncthreads();   // (4) scatter visible

    // ---- coalesced global phase
    {
        f16* hrow = hout + ((size_t)b * TLEN + t0 + row) * 64 + q * 16;
        *(uint4*)&hrow[0] = *(const uint4*)&hprvT[row * LSTR + q * 16];
        *(uint4*)&hrow[8] = *(const uint4*)&hprvT[row * LSTR + q * 16 + 8];
    }
    {
        f16* drow = sb + (size_t)(t0 + row) * 128 + q * 32;
        const f16* incb = ((q < 2) ? outT : extT) + row * LSTR + (q & 1) * 32;
        if (first) {
            #pragma unroll
            for (int k = 0; k < 4; ++k)
                *(uint4*)&drow[k * 8] = *(const uint4*)&incb[k * 8];
        } else {
            #pragma unroll
            for (int k = 0; k < 4; ++k) {
                union { f16 h[8]; uint4 u; } o_, i_, n_;
                o_.u = sold[k];
                i_.u = *(const uint4*)&incb[k * 8];
                #pragma unroll
                for (int j = 0; j < 8; ++j)
                    n_.h[j] = (f16)((float)o_.h[j] + (float)i_.h[j]);
                *(uint4*)&drow[k * 8] = n_.u;
            }
        }
    }
}

// ---------------- head: relu(post) -> relu(o1) -> o2, f16 MFMA ----------------
__global__ __launch_bounds__(256, 4) void head_mfma(
    const f16* __restrict__ skipw, const f16* __restrict__ wpostp,
    const f16* __restrict__ wo1pp, const float* __restrict__ wo2,
    const float* __restrict__ b_post, const float* __restrict__ b_o1,
    const float* __restrict__ b_o2, float* __restrict__ out)
{
    __shared__ f16 sT[64 * 136];
    int tid = threadIdx.x, lane = tid & 63, wv = tid >> 6;
    int kg = lane >> 4, ln = lane & 15;
    int gt = (blockIdx.x & 7) * 128 + (blockIdx.x >> 3);  // same XCD chunking as layers
    int b = gt >> 8, t0 = (gt & 255) * 64;
    int trow = wv * 16 + ln;
    int tl = t0 + trow;
    const f16* sb = skipw + (size_t)b * TLEN * 128;

    f16x8 bfr[4];
    #pragma unroll
    for (int kt = 0; kt < 4; ++kt)
        bfr[kt] = *(const f16x8*)&sb[(size_t)tl * 128 + kt * 32 + kg * 8];
    f32x4 acc[8];
    #pragma unroll
    for (int mt = 0; mt < 8; ++mt) {
        float4 bv = *(const float4*)(b_post + mt * 16 + kg * 4);
        acc[mt] = (f32x4){bv.x, bv.y, bv.z, bv.w};
    }
    #pragma unroll
    for (int mt = 0; mt < 8; ++mt)
        #pragma unroll
        for (int kt = 0; kt < 4; ++kt) {
            f16x8 a = *(const f16x8*)&wpostp[(size_t)((mt * 4 + kt) * 64 + lane) * 8];
            acc[mt] = __builtin_amdgcn_mfma_f32_16x16x32_f16(a, bfr[kt], acc[mt], 0, 0, 0);
        }
    #pragma unroll
    for (int mt = 0; mt < 8; ++mt) {
        union { f16 h[4]; uint2 u; } pk;
        #pragma unroll
        for (int r = 0; r < 4; ++r)
            pk.h[r] = (f16)fmaxf(acc[mt][r], 0.f);
        *(uint2*)&sT[trow * 136 + mt * 16 + kg * 4] = pk.u;
    }

    f16x8 b2[4];
    #pragma unroll
    for (int kt = 0; kt < 4; ++kt)
        b2[kt] = *(const f16x8*)&sT[trow * 136 + kt * 32 + kg * 8];
    f32x4 acc2[8];
    #pragma unroll
    for (int mt = 0; mt < 8; ++mt) {
        float4 bv = *(const float4*)(b_o1 + mt * 16 + kg * 4);
        acc2[mt] = (f32x4){bv.x, bv.y, bv.z, bv.w};
    }
    #pragma unroll
    for (int mt = 0; mt < 8; ++mt)
        #pragma unroll
        for (int kt = 0; kt < 4; ++kt) {
            f16x8 a = *(const f16x8*)&wo1pp[(size_t)((mt * 4 + kt) * 64 + lane) * 8];
            acc2[mt] = __builtin_amdgcn_mfma_f32_16x16x32_f16(a, b2[kt], acc2[mt], 0, 0, 0);
        }

    float part = 0.f;
    #pragma unroll
    for (int mt = 0; mt < 8; ++mt) {
        float4 wv4 = *(const float4*)(wo2 + mt * 16 + kg * 4);
        part = fmaf(wv4.x, fmaxf(acc2[mt][0], 0.f), part);
        part = fmaf(wv4.y, fmaxf(acc2[mt][1], 0.f), part);
        part = fmaf(wv4.z, fmaxf(acc2[mt][2], 0.f), part);
        part = fmaf(wv4.w, fmaxf(acc2[mt][3], 0.f), part);
    }
    part += __shfl_xor(part, 16);
    part += __shfl_xor(part, 32);
    if (lane < 16)
        out[(size_t)b * TLEN + tl] = part + b_o2[0];
}

// ---------------- host ----------------
extern "C" void kernel_launch(void* const* d_in, const int* in_sizes, int n_in,
                              void* d_out, int out_size, void* d_ws, size_t ws_size,
                              hipStream_t stream) {
    const float* x        = (const float*)d_in[0];
    const float* w_causal = (const float*)d_in[1];
    const float* b_causal = (const float*)d_in[2];
    const float* Wf       = (const float*)d_in[3];
    const float* bf       = (const float*)d_in[4];
    const float* Wg       = (const float*)d_in[5];
    const float* bg       = (const float*)d_in[6];
    const float* Wr       = (const float*)d_in[7];
    const float* br       = (const float*)d_in[8];
    const float* Ws       = (const float*)d_in[9];
    const float* bs       = (const float*)d_in[10];
    const float* w_post   = (const float*)d_in[11];
    const float* b_post   = (const float*)d_in[12];
    const float* w_o1     = (const float*)d_in[13];
    const float* b_o1     = (const float*)d_in[14];
    const float* w_o2     = (const float*)d_in[15];
    const float* b_o2     = (const float*)d_in[16];

    f16* p     = (f16*)d_ws;
    f16* h0    = p;  p += (size_t)NB * TLEN * 64;
    f16* h1    = p;  p += (size_t)NB * TLEN * 64;
    f16* skipw = p;  p += (size_t)NB * TLEN * 128;
    f16* wfgp  = p;  p += (size_t)NLAYERS * 8 * 4 * 64 * 8;
    f16* wrsp  = p;  p += (size_t)NLAYERS * 12 * 2 * 64 * 8;
    f16* wpostp= p;  p += (size_t)8 * 4 * 64 * 8;
    f16* wo1pp = p;

    pack_all<<<436, 256, 0, stream>>>(Wf, Wg, Wr, Ws, w_post, w_o1,
                                      wfgp, wrsp, wpostp, wo1pp);
    init_f16<<<NB * TLEN / 256, 256, 0, stream>>>(x, w_causal, b_causal, h0);

    f16* hin = h0;
    f16* hout = h1;
    for (int i = 0; i < NLAYERS; ++i) {
        int d = 1 << (i % 10);
        layer_mfma<<<1024, 256, 0, stream>>>(hin, hout, skipw, wfgp, wrsp,
                                             bf, bg, br, bs, i, d, i == 0);
        f16* tmp = hin; hin = hout; hout = tmp;
    }
    head_mfma<<<1024, 256, 0, stream>>>(skipw, wpostp, wo1pp, w_o2,
                                        b_post, b_o1, b_o2, (float*)d_out);
}